// Round 8
// baseline (35.428 us; speedup 1.0000x reference)
//
#include <hip/hip_runtime.h>
#include <cstddef>

namespace {

constexpr int B     = 512;
constexpr int C     = 2047;   // 2^(DEPTH+1) - 1
constexpr int L     = 4;
constexpr int BLOCK = 256;
constexpr int NINT  = 1023;   // internal nodes 0..1022

__device__ __forceinline__ float4 ld4(const float* p) {
    return *reinterpret_cast<const float4*>(p);
}
__device__ __forceinline__ void st4f(float* p, const float4 v) {
    *reinterpret_cast<float4*>(p) = v;
}
__device__ __forceinline__ float4 add4(const float4 a, const float4 b) {
    float4 r; r.x = a.x + b.x; r.y = a.y + b.y; r.z = a.z + b.z; r.w = a.w + b.w;
    return r;
}

__device__ __forceinline__ float lse4(float v0, float v1, float v2, float v3) {
    const float m = fmaxf(fmaxf(v0, v1), fmaxf(v2, v3));
    const float s = __expf(v0 - m) + __expf(v1 - m) + __expf(v2 - m) + __expf(v3 - m);
    return m + __logf(s);
}

__device__ __forceinline__ void write_lsm(float* __restrict__ o, const float4 g) {
    const float z = lse4(g.x, g.y, g.z, g.w);
    float4 r; r.x = g.x - z; r.y = g.y - z; r.z = g.z - z; r.w = g.w - z;
    st4f(o, r);
}

// Upward contribution to parent p's alpha from BOTH children; lc0/lc1 are the
// children's (X+alpha) vectors. pairs[p][2p+1], pairs[p][2p+2] are adjacent.
__device__ __forceinline__ float4 up2(const float* __restrict__ pairs, int p,
                                      const float4 lc0, const float4 lc1) {
    const float* __restrict__ t = pairs + ((size_t)p * C + (2 * p + 1)) * 16;
    float4 acc;
    {
        const float4 a = ld4(t + 0), bq = ld4(t + 16);
        acc.x = lse4(a.x + lc0.x, a.y + lc0.y, a.z + lc0.z, a.w + lc0.w)
              + lse4(bq.x + lc1.x, bq.y + lc1.y, bq.z + lc1.z, bq.w + lc1.w);
    }
    {
        const float4 a = ld4(t + 4), bq = ld4(t + 20);
        acc.y = lse4(a.x + lc0.x, a.y + lc0.y, a.z + lc0.z, a.w + lc0.w)
              + lse4(bq.x + lc1.x, bq.y + lc1.y, bq.z + lc1.z, bq.w + lc1.w);
    }
    {
        const float4 a = ld4(t + 8), bq = ld4(t + 24);
        acc.z = lse4(a.x + lc0.x, a.y + lc0.y, a.z + lc0.z, a.w + lc0.w)
              + lse4(bq.x + lc1.x, bq.y + lc1.y, bq.z + lc1.z, bq.w + lc1.w);
    }
    {
        const float4 a = ld4(t + 12), bq = ld4(t + 28);
        acc.w = lse4(a.x + lc0.x, a.y + lc0.y, a.z + lc0.z, a.w + lc0.w)
              + lse4(bq.x + lc1.x, bq.y + lc1.y, bq.z + lc1.z, bq.w + lc1.w);
    }
    return acc;
}

// Downward message into child c from parent p; lp = X[p] + beta[p].
__device__ __forceinline__ float4 dn_msg(const float* __restrict__ pairs,
                                         int c, int p, const float4 lp) {
    const float* __restrict__ t = pairs + ((size_t)c * C + p) * 16;
    const float4 t0 = ld4(t + 0), t1 = ld4(t + 4), t2 = ld4(t + 8), t3 = ld4(t + 12);
    float4 m;
    m.x = lse4(t0.x + lp.x, t0.y + lp.y, t0.z + lp.z, t0.w + lp.w);
    m.y = lse4(t1.x + lp.x, t1.y + lp.y, t1.z + lp.z, t1.w + lp.w);
    m.z = lse4(t2.x + lp.x, t2.y + lp.y, t2.z + lp.z, t2.w + lp.w);
    m.w = lse4(t3.x + lp.x, t3.y + lp.y, t3.z + lp.z, t3.w + lp.w);
    return m;
}

// One block (4 waves) per batch element. Each wave owns one depth-2 subtree
// (roots 3..6; 511 nodes each) and runs its upward (depths 9..2) and downward
// (depths 3..10) sweeps fully wave-synchronously (free wave_barriers). Only
// the depth 0..2 top runs on wave 0, bracketed by the ONLY 2 block barriers.
// LDS holds la[n] = X[n]+alpha[n] and lb[n] = X[n]+beta[n] for internal nodes.
__global__ __launch_bounds__(BLOCK, 2) void treecrf_kernel(
    const float* __restrict__ X,      // (B, C, L)
    const float* __restrict__ pairs,  // (C, C, L, L)
    float* __restrict__ out)          // (B, C, L)
{
    __shared__ float la[NINT * L];    // 16368 B
    __shared__ float lb[NINT * L];    // 16368 B

    const int b    = blockIdx.x;
    const int tid  = threadIdx.x;
    const int w    = tid >> 6;        // wave id = subtree id (root 3+w)
    const int lane = tid & 63;
    const float* __restrict__ Xb = X + (size_t)b * (C * L);
    float* __restrict__ Ob       = out + (size_t)b * (C * L);

    // ===== per-wave upward: parents at abs depth 9 down to 2 =====
    // depth 9: 128 parents/wave (2 per lane); children are leaves (alpha=0).
    #pragma unroll
    for (int k = 0; k < 2; ++k) {
        const int p  = 511 + w * 128 + lane + 64 * k;
        const int c0 = 2 * p + 1;
        const float4 l0 = ld4(Xb + c0 * L);
        const float4 l1 = ld4(Xb + (c0 + 1) * L);
        const float4 a  = up2(pairs, p, l0, l1);
        st4f(&la[p * L], add4(ld4(Xb + p * L), a));
    }
    __builtin_amdgcn_wave_barrier();

    // depths 8..2: 64,32,16,8,4,2,1 parents per wave.
    #pragma unroll 1
    for (int dp = 8; dp >= 2; --dp) {
        const int cnt = 1 << (dp - 2);
        if (lane < cnt) {
            const int p  = ((1 << dp) - 1) + w * cnt + lane;
            const int c0 = 2 * p + 1;
            const float4 l0 = ld4(&la[c0 * L]);
            const float4 l1 = ld4(&la[(c0 + 1) * L]);
            const float4 a  = up2(pairs, p, l0, l1);
            st4f(&la[p * L], add4(ld4(Xb + p * L), a));
        }
        __builtin_amdgcn_wave_barrier();
    }
    __syncthreads();

    // ===== top (wave 0): depths 1,0 upward; root output; downward to depth 2.
    if (tid < 64) {
        if (lane < 2) {  // up, parents 1,2 (children 3..6)
            const int p = 1 + lane;
            const float4 l0 = ld4(&la[(2 * p + 1) * L]);
            const float4 l1 = ld4(&la[(2 * p + 2) * L]);
            const float4 a  = up2(pairs, p, l0, l1);
            st4f(&la[p * L], add4(ld4(Xb + p * L), a));
        }
        __builtin_amdgcn_wave_barrier();
        if (lane == 0) {  // root: alpha, output (beta=0), lb[0]=X[0]
            const float4 l0 = ld4(&la[1 * L]);
            const float4 l1 = ld4(&la[2 * L]);
            const float4 a  = up2(pairs, 0, l0, l1);
            const float4 x0 = ld4(Xb);
            write_lsm(Ob, add4(x0, a));
            st4f(&lb[0], x0);
        }
        __builtin_amdgcn_wave_barrier();
        if (lane < 2) {  // down depth 1: c = 1,2
            const int c = 1 + lane;
            const float4 m = dn_msg(pairs, c, 0, ld4(&lb[0]));
            st4f(&lb[c * L], add4(ld4(Xb + c * L), m));
            write_lsm(Ob + c * L, add4(ld4(&la[c * L]), m));
        }
        __builtin_amdgcn_wave_barrier();
        if (lane < 4) {  // down depth 2: c = 3..6 (subtree roots)
            const int c = 3 + lane;
            const int p = (c - 1) >> 1;
            const float4 m = dn_msg(pairs, c, p, ld4(&lb[p * L]));
            st4f(&lb[c * L], add4(ld4(Xb + c * L), m));
            write_lsm(Ob + c * L, add4(ld4(&la[c * L]), m));
        }
    }
    __syncthreads();

    // ===== per-wave downward: children at abs depth 3..10 =====
    #pragma unroll 1
    for (int dc = 3; dc <= 8; ++dc) {
        const int cnt = 1 << (dc - 2);
        if (lane < cnt) {
            const int c = ((1 << dc) - 1) + w * cnt + lane;
            const int p = (c - 1) >> 1;
            const float4 m = dn_msg(pairs, c, p, ld4(&lb[p * L]));
            st4f(&lb[c * L], add4(ld4(Xb + c * L), m));
            write_lsm(Ob + c * L, add4(ld4(&la[c * L]), m));
        }
        __builtin_amdgcn_wave_barrier();
    }
    // depth 9: 128 per wave.
    #pragma unroll
    for (int k = 0; k < 2; ++k) {
        const int c = 511 + w * 128 + lane + 64 * k;
        const int p = (c - 1) >> 1;
        const float4 m = dn_msg(pairs, c, p, ld4(&lb[p * L]));
        st4f(&lb[c * L], add4(ld4(Xb + c * L), m));
        write_lsm(Ob + c * L, add4(ld4(&la[c * L]), m));
    }
    __builtin_amdgcn_wave_barrier();
    // depth 10: 256 leaves per wave (alpha = 0, no lb needed).
    #pragma unroll
    for (int k = 0; k < 4; ++k) {
        const int c = 1023 + w * 256 + lane + 64 * k;
        const int p = (c - 1) >> 1;
        const float4 m = dn_msg(pairs, c, p, ld4(&lb[p * L]));
        write_lsm(Ob + c * L, add4(ld4(Xb + c * L), m));
    }
}

}  // namespace

extern "C" void kernel_launch(void* const* d_in, const int* in_sizes, int n_in,
                              void* d_out, int out_size, void* d_ws, size_t ws_size,
                              hipStream_t stream) {
    (void)in_sizes; (void)n_in; (void)out_size; (void)d_ws; (void)ws_size;
    const float* X     = (const float*)d_in[0];
    const float* pairs = (const float*)d_in[1];
    float* out         = (float*)d_out;
    treecrf_kernel<<<B, BLOCK, 0, stream>>>(X, pairs, out);
}